// Round 3
// baseline (38.318 us; speedup 1.0000x reference)
//
#include <hip/hip_runtime.h>
#include <math.h>

#define ROWS 32
#define LROW 15104
#define TWIN 128
#define SSH  257
#define NWIN 118
#define TRIM 14848            // LROW - 2*TWIN
#define NW   (ROWS * NWIN)    // 3776 windows
#define SEGS 8
#define SEGLEN (TRIM / SEGS)  // 1856
#define NSEG4 (SEGLEN / 4)    // 464 float4 per segment

// d_ws layout:
//   [0 .. 256)    : float4 partials[ROWS*SEGS]  (sd, sd2, sr, sr2)  = 4 KB
//   [4096 .. )    : u64 acc[0] = fixed-point loss sum, acc[1] = block counter

// ---------------- per-row partial stats (8 segments per row) ----------------
__global__ __launch_bounds__(256) void stats_partial(
        const float* __restrict__ data,
        const float* __restrict__ target,
        float4* __restrict__ partials,
        unsigned long long* __restrict__ acc) {
    int blk = blockIdx.x;          // 0..255
    int row = blk >> 3;
    int seg = blk & 7;
    int tid = threadIdx.x;

    if (blk == 0 && tid == 0) { acc[0] = 0ull; acc[1] = 0ull; }

    const float4* x4 = (const float4*)(data   + row * LROW + TWIN + seg * SEGLEN);
    const float4* r4 = (const float4*)(target + row * LROW + TWIN + seg * SEGLEN);
    float sd = 0.f, sd2 = 0.f, sr = 0.f, sr2 = 0.f;
    for (int i = tid; i < NSEG4; i += 256) {
        float4 a = x4[i], b = r4[i];
        sd  += a.x + a.y + a.z + a.w;
        sd2 += a.x*a.x + a.y*a.y + a.z*a.z + a.w*a.w;
        sr  += b.x + b.y + b.z + b.w;
        sr2 += b.x*b.x + b.y*b.y + b.z*b.z + b.w*b.w;
    }
    __shared__ float sh[4][256];
    sh[0][tid] = sd; sh[1][tid] = sd2; sh[2][tid] = sr; sh[3][tid] = sr2;
    __syncthreads();
    for (int off = 128; off > 0; off >>= 1) {
        if (tid < off) {
            sh[0][tid] += sh[0][tid + off];
            sh[1][tid] += sh[1][tid + off];
            sh[2][tid] += sh[2][tid + off];
            sh[3][tid] += sh[3][tid + off];
        }
        __syncthreads();
    }
    if (tid == 0)
        partials[blk] = make_float4(sh[0][0], sh[1][0], sh[2][0], sh[3][0]);
}

// ---------------- main shifted-L2 loss: 1 wave per window, 4 shifts/lane ----
__global__ __launch_bounds__(256) void loss_kernel(
        const float* __restrict__ data,
        const float* __restrict__ target,
        const float4* __restrict__ partials,
        unsigned long long* __restrict__ acc,
        float* __restrict__ out) {
    int tid  = threadIdx.x;
    int wave = tid >> 6;
    int lane = tid & 63;
    int widx = blockIdx.x * 4 + wave;       // 944 blocks * 4 = 3776, exact
    int row  = widx / NWIN;
    int n    = widx % NWIN;

    // ---- recompute row scale from the 8 partials (wave-uniform) ----
    float scale;
    {
        const float4* pr = partials + row * SEGS;
        float sd = 0.f, sd2 = 0.f, sr = 0.f, sr2 = 0.f;
        #pragma unroll
        for (int i = 0; i < SEGS; ++i) {
            float4 p = pr[i];
            sd += p.x; sd2 += p.y; sr += p.z; sr2 += p.w;
        }
        const float inv = 1.0f / (float)TRIM;
        float md = sd * inv, mr = sr * inv;
        float vx = fmaxf(sd2 * inv - md * md, 0.f);
        float vr = fmaxf(sr2 * inv - mr * mr, 0.f);
        float mag_x = sqrtf(vx), mag_r = sqrtf(vr);
        float mag_min = fminf(mag_x, mag_r);
        scale = 1.0f / (sqrtf(mag_min * mag_r) + 0.001f);
    }

    __shared__ float xs[4][TWIN];
    __shared__ float ys[4][3 * TWIN];

    const float* xr = data   + row * LROW + n * TWIN;
    const float* rr = target + row * LROW;
    int base = n * TWIN;

    // stage x: 128 floats, 2 per lane
    {
        float2 v = *(const float2*)(xr + 2 * lane);
        xs[wave][2 * lane]     = v.x * scale;
        xs[wave][2 * lane + 1] = v.y * scale;
    }
    // stage y: 384 floats = 96 float4 (4-aligned; fully in or fully out)
    for (int j = lane; j < 96; j += 64) {
        int g0 = base + 4 * j - TWIN;
        float4 v = make_float4(0.f, 0.f, 0.f, 0.f);
        if (g0 >= 0 && g0 < LROW) v = *(const float4*)(rr + g0);
        *(float4*)&ys[wave][4 * j] =
            make_float4(v.x * scale, v.y * scale, v.z * scale, v.w * scale);
    }
    // wave-private LDS region: no __syncthreads needed before in-wave reads.

    // ---- cooperative pass: sx = sum x^2, and raw s=256 sum of squares ----
    float sx, part;
    {
        float xa = xs[wave][lane], xb = xs[wave][lane + 64];
        float ya = ys[wave][256 + lane], yb = ys[wave][320 + lane];
        float d1 = xa - ya, d2 = xb - yb;
        part = d1 * d1 + d2 * d2;
        sx   = xa * xa + xb * xb;
        #pragma unroll
        for (int off = 32; off > 0; off >>= 1) {
            part += __shfl_xor(part, off, 64);
            sx   += __shfl_xor(sx,   off, 64);
        }
    }

    const float4* xs4 = (const float4*)xs[wave];
    const float4* ys4 = (const float4*)ys[wave];

    // shifts s0..s0+3, s0 = 4*lane (covers s=0..255)
    float4 yv0 = ys4[lane];
    float yf0 = yv0.x, yf1 = yv0.y, yf2 = yv0.z;
    float c0 = 0.f, c1 = 0.f, c2 = 0.f, c3 = 0.f;
    float q = 0.f;                       // sum y^2 over window at s0

    #pragma unroll
    for (int kb = 0; kb < 32; ++kb) {
        float4 xv  = xs4[kb];            // lane-uniform broadcast
        float4 yv1 = ys4[lane + kb + 1];
        c0 += xv.x*yv0.x + xv.y*yv0.y + xv.z*yv0.z + xv.w*yv0.w;
        c1 += xv.x*yv0.y + xv.y*yv0.z + xv.z*yv0.w + xv.w*yv1.x;
        c2 += xv.x*yv0.z + xv.y*yv0.w + xv.z*yv1.x + xv.w*yv1.y;
        c3 += xv.x*yv0.w + xv.y*yv1.x + xv.z*yv1.y + xv.w*yv1.z;
        q  += yv0.x*yv0.x + yv0.y*yv0.y + yv0.z*yv0.z + yv0.w*yv0.w;
        yv0 = yv1;
    }
    // yv0 = y[s0+128 .. s0+131]
    float sy0 = q;
    float sy1 = sy0 - yf0*yf0 + yv0.x*yv0.x;
    float sy2 = sy1 - yf1*yf1 + yv0.y*yv0.y;
    float sy3 = sy2 - yf2*yf2 + yv0.z*yv0.z;

    const float inv = 1.0f / (float)TWIN;
    int   s0  = lane * 4;
    float lmin = 1e30f;
    {
        float mse, ph, cp, bw, w;
        mse = (sx - 2.f*c0 + sy0) * inv;
        ph  = (float)(s0 + 0) * (float)(M_PI / 128.0);
        cp  = __cosf(ph); bw = 0.42f - 0.5f*cp + 0.08f*(2.f*cp*cp - 1.f);
        w   = 100.f * (1.f - bw);
        lmin = fminf(lmin, (mse + 1.f) * (w + 1.f) - 1.f);
        mse = (sx - 2.f*c1 + sy1) * inv;
        ph  = (float)(s0 + 1) * (float)(M_PI / 128.0);
        cp  = __cosf(ph); bw = 0.42f - 0.5f*cp + 0.08f*(2.f*cp*cp - 1.f);
        w   = 100.f * (1.f - bw);
        lmin = fminf(lmin, (mse + 1.f) * (w + 1.f) - 1.f);
        mse = (sx - 2.f*c2 + sy2) * inv;
        ph  = (float)(s0 + 2) * (float)(M_PI / 128.0);
        cp  = __cosf(ph); bw = 0.42f - 0.5f*cp + 0.08f*(2.f*cp*cp - 1.f);
        w   = 100.f * (1.f - bw);
        lmin = fminf(lmin, (mse + 1.f) * (w + 1.f) - 1.f);
        mse = (sx - 2.f*c3 + sy3) * inv;
        ph  = (float)(s0 + 3) * (float)(M_PI / 128.0);
        cp  = __cosf(ph); bw = 0.42f - 0.5f*cp + 0.08f*(2.f*cp*cp - 1.f);
        w   = 100.f * (1.f - bw);
        lmin = fminf(lmin, (mse + 1.f) * (w + 1.f) - 1.f);
    }

    // s = 256: w[256] = 100 exactly
    {
        float mse256 = part * inv;
        float l256 = (mse256 + 1.f) * 101.f - 1.f;
        lmin = fminf(lmin, l256);
    }
    // wave min-reduce
    #pragma unroll
    for (int off = 32; off > 0; off >>= 1)
        lmin = fminf(lmin, __shfl_xor(lmin, off, 64));

    __shared__ float wl[4];
    if (lane == 0) wl[wave] = lmin;
    __syncthreads();
    if (tid == 0) {
        double s = (double)wl[0] + (double)wl[1] + (double)wl[2] + (double)wl[3];
        unsigned long long add =
            (unsigned long long)(long long)(s * 4294967296.0);
        atomicAdd(&acc[0], add);
        __threadfence();
        unsigned long long old = atomicAdd(&acc[1], 1ull);
        if (old == (unsigned long long)(gridDim.x - 1)) {
            __threadfence();
            unsigned long long tot = atomicAdd(&acc[0], 0ull);
            out[0] = (float)((double)(long long)tot / 4294967296.0
                             / (double)NW);
        }
    }
}

extern "C" void kernel_launch(void* const* d_in, const int* in_sizes, int n_in,
                              void* d_out, int out_size, void* d_ws, size_t ws_size,
                              hipStream_t stream) {
    const float* data   = (const float*)d_in[0];
    const float* target = (const float*)d_in[1];
    float4* partials = (float4*)d_ws;
    unsigned long long* acc =
        (unsigned long long*)((char*)d_ws + 4096);

    stats_partial<<<ROWS * SEGS, 256, 0, stream>>>(data, target, partials, acc);
    loss_kernel<<<NW / 4, 256, 0, stream>>>(data, target, partials, acc,
                                            (float*)d_out);
}

// Round 4
// 19.541 us; speedup vs baseline: 1.9609x; 1.9609x over previous
//
#include <hip/hip_runtime.h>
#include <math.h>

#define ROWS 32
#define LROW 15104
#define TWIN 128
#define SSH  257
#define NWIN 118
#define TRIM 14848            // LROW - 2*TWIN
#define NW   (ROWS * NWIN)    // 3776 windows
#define NBLK (NW / 4)         // 944 loss blocks
#define SEGS 8
#define SEGLEN (TRIM / SEGS)  // 1856
#define NSEG4 (SEGLEN / 4)    // 464 float4 per segment

// d_ws layout:
//   [0    .. 4096)  : float4 partials[ROWS*SEGS] (sd, sd2, sr, sr2)
//   [8192 .. )      : float blocksums[NBLK]

// ---------------- per-row partial stats (8 segments per row) ----------------
__global__ __launch_bounds__(256) void stats_partial(
        const float* __restrict__ data,
        const float* __restrict__ target,
        float4* __restrict__ partials) {
    int blk = blockIdx.x;          // 0..255
    int row = blk >> 3;
    int seg = blk & 7;
    int tid = threadIdx.x;

    const float4* x4 = (const float4*)(data   + row * LROW + TWIN + seg * SEGLEN);
    const float4* r4 = (const float4*)(target + row * LROW + TWIN + seg * SEGLEN);
    float sd = 0.f, sd2 = 0.f, sr = 0.f, sr2 = 0.f;
    for (int i = tid; i < NSEG4; i += 256) {
        float4 a = x4[i], b = r4[i];
        sd  += a.x + a.y + a.z + a.w;
        sd2 += a.x*a.x + a.y*a.y + a.z*a.z + a.w*a.w;
        sr  += b.x + b.y + b.z + b.w;
        sr2 += b.x*b.x + b.y*b.y + b.z*b.z + b.w*b.w;
    }
    __shared__ float sh[4][256];
    sh[0][tid] = sd; sh[1][tid] = sd2; sh[2][tid] = sr; sh[3][tid] = sr2;
    __syncthreads();
    for (int off = 128; off > 0; off >>= 1) {
        if (tid < off) {
            sh[0][tid] += sh[0][tid + off];
            sh[1][tid] += sh[1][tid + off];
            sh[2][tid] += sh[2][tid + off];
            sh[3][tid] += sh[3][tid + off];
        }
        __syncthreads();
    }
    if (tid == 0)
        partials[blk] = make_float4(sh[0][0], sh[1][0], sh[2][0], sh[3][0]);
}

// ---------------- main shifted-L2 loss: 1 wave per window, 4 shifts/lane ----
__global__ __launch_bounds__(256) void loss_kernel(
        const float* __restrict__ data,
        const float* __restrict__ target,
        const float4* __restrict__ partials,
        float* __restrict__ blocksums) {
    int tid  = threadIdx.x;
    int wave = tid >> 6;
    int lane = tid & 63;
    int widx = blockIdx.x * 4 + wave;       // 944 blocks * 4 = 3776, exact
    int row  = widx / NWIN;
    int n    = widx % NWIN;

    // ---- recompute row scale from the 8 partials (wave-uniform, L2-hit) ----
    float scale;
    {
        const float4* pr = partials + row * SEGS;
        float sd = 0.f, sd2 = 0.f, sr = 0.f, sr2 = 0.f;
        #pragma unroll
        for (int i = 0; i < SEGS; ++i) {
            float4 p = pr[i];
            sd += p.x; sd2 += p.y; sr += p.z; sr2 += p.w;
        }
        const float inv = 1.0f / (float)TRIM;
        float md = sd * inv, mr = sr * inv;
        float vx = fmaxf(sd2 * inv - md * md, 0.f);
        float vr = fmaxf(sr2 * inv - mr * mr, 0.f);
        float mag_x = sqrtf(vx), mag_r = sqrtf(vr);
        float mag_min = fminf(mag_x, mag_r);
        scale = 1.0f / (sqrtf(mag_min * mag_r) + 0.001f);
    }

    __shared__ float xs[4][TWIN];
    __shared__ float ys[4][3 * TWIN];

    const float* xr = data   + row * LROW + n * TWIN;
    const float* rr = target + row * LROW;
    int base = n * TWIN;

    // stage x: 128 floats, 2 per lane
    {
        float2 v = *(const float2*)(xr + 2 * lane);
        xs[wave][2 * lane]     = v.x * scale;
        xs[wave][2 * lane + 1] = v.y * scale;
    }
    // stage y: 384 floats = 96 float4 (4-aligned; fully in or fully out)
    for (int j = lane; j < 96; j += 64) {
        int g0 = base + 4 * j - TWIN;
        float4 v = make_float4(0.f, 0.f, 0.f, 0.f);
        if (g0 >= 0 && g0 < LROW) v = *(const float4*)(rr + g0);
        *(float4*)&ys[wave][4 * j] =
            make_float4(v.x * scale, v.y * scale, v.z * scale, v.w * scale);
    }
    // wave-private LDS region: no __syncthreads needed before in-wave reads.

    // ---- cooperative pass: sx = sum x^2, and raw s=256 sum of squares ----
    float sx, part;
    {
        float xa = xs[wave][lane], xb = xs[wave][lane + 64];
        float ya = ys[wave][256 + lane], yb = ys[wave][320 + lane];
        float d1 = xa - ya, d2 = xb - yb;
        part = d1 * d1 + d2 * d2;
        sx   = xa * xa + xb * xb;
        #pragma unroll
        for (int off = 32; off > 0; off >>= 1) {
            part += __shfl_xor(part, off, 64);
            sx   += __shfl_xor(sx,   off, 64);
        }
    }

    const float4* xs4 = (const float4*)xs[wave];
    const float4* ys4 = (const float4*)ys[wave];

    // shifts s0..s0+3, s0 = 4*lane (covers s=0..255)
    float4 yv0 = ys4[lane];
    float yf0 = yv0.x, yf1 = yv0.y, yf2 = yv0.z;
    float c0 = 0.f, c1 = 0.f, c2 = 0.f, c3 = 0.f;
    float q = 0.f;                       // sum y^2 over window at s0

    #pragma unroll
    for (int kb = 0; kb < 32; ++kb) {
        float4 xv  = xs4[kb];            // lane-uniform broadcast
        float4 yv1 = ys4[lane + kb + 1];
        c0 += xv.x*yv0.x + xv.y*yv0.y + xv.z*yv0.z + xv.w*yv0.w;
        c1 += xv.x*yv0.y + xv.y*yv0.z + xv.z*yv0.w + xv.w*yv1.x;
        c2 += xv.x*yv0.z + xv.y*yv0.w + xv.z*yv1.x + xv.w*yv1.y;
        c3 += xv.x*yv0.w + xv.y*yv1.x + xv.z*yv1.y + xv.w*yv1.z;
        q  += yv0.x*yv0.x + yv0.y*yv0.y + yv0.z*yv0.z + yv0.w*yv0.w;
        yv0 = yv1;
    }
    // yv0 = y[s0+128 .. s0+131]
    float sy0 = q;
    float sy1 = sy0 - yf0*yf0 + yv0.x*yv0.x;
    float sy2 = sy1 - yf1*yf1 + yv0.y*yv0.y;
    float sy3 = sy2 - yf2*yf2 + yv0.z*yv0.z;

    const float inv = 1.0f / (float)TWIN;
    int   s0  = lane * 4;
    float lmin = 1e30f;
    {
        float mse, ph, cp, bw, w;
        mse = (sx - 2.f*c0 + sy0) * inv;
        ph  = (float)(s0 + 0) * (float)(M_PI / 128.0);
        cp  = __cosf(ph); bw = 0.42f - 0.5f*cp + 0.08f*(2.f*cp*cp - 1.f);
        w   = 100.f * (1.f - bw);
        lmin = fminf(lmin, (mse + 1.f) * (w + 1.f) - 1.f);
        mse = (sx - 2.f*c1 + sy1) * inv;
        ph  = (float)(s0 + 1) * (float)(M_PI / 128.0);
        cp  = __cosf(ph); bw = 0.42f - 0.5f*cp + 0.08f*(2.f*cp*cp - 1.f);
        w   = 100.f * (1.f - bw);
        lmin = fminf(lmin, (mse + 1.f) * (w + 1.f) - 1.f);
        mse = (sx - 2.f*c2 + sy2) * inv;
        ph  = (float)(s0 + 2) * (float)(M_PI / 128.0);
        cp  = __cosf(ph); bw = 0.42f - 0.5f*cp + 0.08f*(2.f*cp*cp - 1.f);
        w   = 100.f * (1.f - bw);
        lmin = fminf(lmin, (mse + 1.f) * (w + 1.f) - 1.f);
        mse = (sx - 2.f*c3 + sy3) * inv;
        ph  = (float)(s0 + 3) * (float)(M_PI / 128.0);
        cp  = __cosf(ph); bw = 0.42f - 0.5f*cp + 0.08f*(2.f*cp*cp - 1.f);
        w   = 100.f * (1.f - bw);
        lmin = fminf(lmin, (mse + 1.f) * (w + 1.f) - 1.f);
    }

    // s = 256: w[256] = 100 exactly
    {
        float mse256 = part * inv;
        float l256 = (mse256 + 1.f) * 101.f - 1.f;
        lmin = fminf(lmin, l256);
    }
    // wave min-reduce
    #pragma unroll
    for (int off = 32; off > 0; off >>= 1)
        lmin = fminf(lmin, __shfl_xor(lmin, off, 64));

    __shared__ float wl[4];
    if (lane == 0) wl[wave] = lmin;
    __syncthreads();
    if (tid == 0) {
        // fixed-order sum of the 4 window losses -> deterministic
        blocksums[blockIdx.x] =
            ((wl[0] + wl[1]) + (wl[2] + wl[3]));
    }
}

// ---------------- final mean ----------------
__global__ __launch_bounds__(256) void finish_kernel(
        const float* __restrict__ blocksums,
        float* __restrict__ out) {
    int tid = threadIdx.x;
    float s = 0.f;
    for (int i = tid; i < NBLK; i += 256) s += blocksums[i];
    __shared__ float sh[256];
    sh[tid] = s;
    __syncthreads();
    for (int off = 128; off > 0; off >>= 1) {
        if (tid < off) sh[tid] += sh[tid + off];
        __syncthreads();
    }
    if (tid == 0) out[0] = sh[0] / (float)NW;
}

extern "C" void kernel_launch(void* const* d_in, const int* in_sizes, int n_in,
                              void* d_out, int out_size, void* d_ws, size_t ws_size,
                              hipStream_t stream) {
    const float* data   = (const float*)d_in[0];
    const float* target = (const float*)d_in[1];
    float4* partials  = (float4*)d_ws;
    float*  blocksums = (float*)((char*)d_ws + 8192);

    stats_partial<<<ROWS * SEGS, 256, 0, stream>>>(data, target, partials);
    loss_kernel<<<NBLK, 256, 0, stream>>>(data, target, partials, blocksums);
    finish_kernel<<<1, 256, 0, stream>>>(blocksums, (float*)d_out);
}

// Round 5
// 18.393 us; speedup vs baseline: 2.0832x; 1.0624x over previous
//
#include <hip/hip_runtime.h>
#include <math.h>

#define ROWS 32
#define LROW 15104
#define TWIN 128
#define NWIN 118
#define TRIM 14848              // LROW - 2*TWIN
#define NW   (ROWS * NWIN)      // 3776 real windows
#define WPB  8                  // windows per block (one per wave)
#define BPR  15                 // blocks per row (8*15=120 >= 118, 2 masked)
#define NBLK (ROWS * BPR)       // 480
#define XPAN (WPB * TWIN)       // 1024 floats
#define YPAN ((WPB + 3) * TWIN) // 1408 floats

// ---------------- fused: row stats + shifted-L2 over 8 windows ----------------
__global__ __launch_bounds__(512) void loss_fused(
        const float* __restrict__ data,
        const float* __restrict__ target,
        float* __restrict__ blocksums) {
    // XCD-chunked swizzle: HW round-robins blockIdx.x % 8 across XCDs, so
    // logical blocks i*60..i*60+59 (4 full rows) land on one XCD -> row
    // re-reads are XCD-local L2 hits.  480 = 8 * 60, bijective.
    int b0 = blockIdx.x;
    int b  = (b0 & 7) * (NBLK / 8) + (b0 >> 3);
    int row = b / BPR;
    int n0  = (b % BPR) * WPB;
    int tid  = threadIdx.x;
    int wave = tid >> 6;
    int lane = tid & 63;

    __shared__ float xs[XPAN];
    __shared__ float ys[YPAN];
    __shared__ float4 wsum[8];
    __shared__ float s_scale;
    __shared__ float wl[8];

    const float* xrow = data   + row * LROW;
    const float* rrow = target + row * LROW;

    // ---- Phase A: full-row stats (redundant per block; L2-resident) ----
    {
        const float4* x4 = (const float4*)(xrow + TWIN);
        const float4* r4 = (const float4*)(rrow + TWIN);
        float sd = 0.f, sd2 = 0.f, sr = 0.f, sr2 = 0.f;
        for (int i = tid; i < TRIM / 4; i += 512) {
            float4 a = x4[i], bv = r4[i];
            sd  += a.x + a.y + a.z + a.w;
            sd2 += a.x*a.x + a.y*a.y + a.z*a.z + a.w*a.w;
            sr  += bv.x + bv.y + bv.z + bv.w;
            sr2 += bv.x*bv.x + bv.y*bv.y + bv.z*bv.z + bv.w*bv.w;
        }
        #pragma unroll
        for (int off = 32; off > 0; off >>= 1) {
            sd  += __shfl_xor(sd,  off, 64);
            sd2 += __shfl_xor(sd2, off, 64);
            sr  += __shfl_xor(sr,  off, 64);
            sr2 += __shfl_xor(sr2, off, 64);
        }
        if (lane == 0) wsum[wave] = make_float4(sd, sd2, sr, sr2);
    }
    __syncthreads();
    if (tid == 0) {
        float sd = 0.f, sd2 = 0.f, sr = 0.f, sr2 = 0.f;
        #pragma unroll
        for (int i = 0; i < 8; ++i) {
            float4 p = wsum[i];
            sd += p.x; sd2 += p.y; sr += p.z; sr2 += p.w;
        }
        const float inv = 1.0f / (float)TRIM;
        float md = sd * inv, mr = sr * inv;
        float vx = fmaxf(sd2 * inv - md * md, 0.f);
        float vr = fmaxf(sr2 * inv - mr * mr, 0.f);
        float mag_x = sqrtf(vx), mag_r = sqrtf(vr);
        float mag_min = fminf(mag_x, mag_r);
        s_scale = 1.0f / (sqrtf(mag_min * mag_r) + 0.001f);
    }
    __syncthreads();
    float scale = s_scale;

    // ---- Phase B: stage shared panels (pre-scaled) ----
    for (int j = tid; j < XPAN / 4; j += 512) {
        int g = n0 * TWIN + 4 * j;          // row-local float index
        float4 v = make_float4(0.f, 0.f, 0.f, 0.f);
        if (g < LROW) v = *(const float4*)(xrow + g);
        *(float4*)&xs[4 * j] =
            make_float4(v.x * scale, v.y * scale, v.z * scale, v.w * scale);
    }
    for (int j = tid; j < YPAN / 4; j += 512) {
        int g = (n0 - 1) * TWIN + 4 * j;    // row-local, may be <0 or >=LROW
        float4 v = make_float4(0.f, 0.f, 0.f, 0.f);
        if (g >= 0 && g < LROW) v = *(const float4*)(rrow + g);
        *(float4*)&ys[4 * j] =
            make_float4(v.x * scale, v.y * scale, v.z * scale, v.w * scale);
    }
    __syncthreads();

    // ---- Phase C: wave `wave` computes window n0+wave ----
    int n = n0 + wave;
    float lmin = 0.f;                       // masked waves contribute 0
    if (n < NWIN) {
        const float* xw = xs + wave * TWIN;
        const float* yw = ys + wave * TWIN; // window y-origin = (n-1)*128 global

        // cooperative: sx = sum x^2, and s=256 sum of squared diffs
        float sx, part;
        {
            float xa = xw[lane], xb = xw[lane + 64];
            float ya = yw[256 + lane], yb = yw[320 + lane];
            float d1 = xa - ya, d2 = xb - yb;
            part = d1 * d1 + d2 * d2;
            sx   = xa * xa + xb * xb;
            #pragma unroll
            for (int off = 32; off > 0; off >>= 1) {
                part += __shfl_xor(part, off, 64);
                sx   += __shfl_xor(sx,   off, 64);
            }
        }

        const float4* xs4 = (const float4*)xw;
        const float4* ys4 = (const float4*)yw;

        // shifts s0..s0+3, s0 = 4*lane (covers s=0..255)
        float4 yv0 = ys4[lane];
        float yf0 = yv0.x, yf1 = yv0.y, yf2 = yv0.z;
        float c0 = 0.f, c1 = 0.f, c2 = 0.f, c3 = 0.f;
        float q = 0.f;                      // sum y^2 over window at s0

        #pragma unroll
        for (int kb = 0; kb < 32; ++kb) {
            float4 xv  = xs4[kb];           // wave-uniform broadcast
            float4 yv1 = ys4[lane + kb + 1];
            c0 += xv.x*yv0.x + xv.y*yv0.y + xv.z*yv0.z + xv.w*yv0.w;
            c1 += xv.x*yv0.y + xv.y*yv0.z + xv.z*yv0.w + xv.w*yv1.x;
            c2 += xv.x*yv0.z + xv.y*yv0.w + xv.z*yv1.x + xv.w*yv1.y;
            c3 += xv.x*yv0.w + xv.y*yv1.x + xv.z*yv1.y + xv.w*yv1.z;
            q  += yv0.x*yv0.x + yv0.y*yv0.y + yv0.z*yv0.z + yv0.w*yv0.w;
            yv0 = yv1;
        }
        float sy0 = q;
        float sy1 = sy0 - yf0*yf0 + yv0.x*yv0.x;
        float sy2 = sy1 - yf1*yf1 + yv0.y*yv0.y;
        float sy3 = sy2 - yf2*yf2 + yv0.z*yv0.z;

        const float inv = 1.0f / (float)TWIN;
        int   s0  = lane * 4;
        lmin = 1e30f;
        {
            float mse, ph, cp, bw, w;
            mse = (sx - 2.f*c0 + sy0) * inv;
            ph  = (float)(s0 + 0) * (float)(M_PI / 128.0);
            cp  = __cosf(ph); bw = 0.42f - 0.5f*cp + 0.08f*(2.f*cp*cp - 1.f);
            w   = 100.f * (1.f - bw);
            lmin = fminf(lmin, (mse + 1.f) * (w + 1.f) - 1.f);
            mse = (sx - 2.f*c1 + sy1) * inv;
            ph  = (float)(s0 + 1) * (float)(M_PI / 128.0);
            cp  = __cosf(ph); bw = 0.42f - 0.5f*cp + 0.08f*(2.f*cp*cp - 1.f);
            w   = 100.f * (1.f - bw);
            lmin = fminf(lmin, (mse + 1.f) * (w + 1.f) - 1.f);
            mse = (sx - 2.f*c2 + sy2) * inv;
            ph  = (float)(s0 + 2) * (float)(M_PI / 128.0);
            cp  = __cosf(ph); bw = 0.42f - 0.5f*cp + 0.08f*(2.f*cp*cp - 1.f);
            w   = 100.f * (1.f - bw);
            lmin = fminf(lmin, (mse + 1.f) * (w + 1.f) - 1.f);
            mse = (sx - 2.f*c3 + sy3) * inv;
            ph  = (float)(s0 + 3) * (float)(M_PI / 128.0);
            cp  = __cosf(ph); bw = 0.42f - 0.5f*cp + 0.08f*(2.f*cp*cp - 1.f);
            w   = 100.f * (1.f - bw);
            lmin = fminf(lmin, (mse + 1.f) * (w + 1.f) - 1.f);
        }
        // s = 256: w[256] = 100 exactly
        {
            float mse256 = part * inv;
            lmin = fminf(lmin, (mse256 + 1.f) * 101.f - 1.f);
        }
        #pragma unroll
        for (int off = 32; off > 0; off >>= 1)
            lmin = fminf(lmin, __shfl_xor(lmin, off, 64));
    }

    if (lane == 0) wl[wave] = lmin;
    __syncthreads();
    if (tid == 0) {
        float s = 0.f;
        #pragma unroll
        for (int i = 0; i < 8; ++i) s += wl[i];   // fixed order: deterministic
        blocksums[b] = s;
    }
}

// ---------------- final mean ----------------
__global__ __launch_bounds__(256) void finish_kernel(
        const float* __restrict__ blocksums,
        float* __restrict__ out) {
    int tid = threadIdx.x;
    float s = 0.f;
    for (int i = tid; i < NBLK; i += 256) s += blocksums[i];
    __shared__ float sh[256];
    sh[tid] = s;
    __syncthreads();
    for (int off = 128; off > 0; off >>= 1) {
        if (tid < off) sh[tid] += sh[tid + off];
        __syncthreads();
    }
    if (tid == 0) out[0] = sh[0] / (float)NW;
}

extern "C" void kernel_launch(void* const* d_in, const int* in_sizes, int n_in,
                              void* d_out, int out_size, void* d_ws, size_t ws_size,
                              hipStream_t stream) {
    const float* data   = (const float*)d_in[0];
    const float* target = (const float*)d_in[1];
    float* blocksums = (float*)d_ws;

    loss_fused<<<NBLK, 512, 0, stream>>>(data, target, blocksums);
    finish_kernel<<<1, 256, 0, stream>>>(blocksums, (float*)d_out);
}